// Round 6
// baseline (303.097 us; speedup 1.0000x reference)
//
#include <hip/hip_runtime.h>
#include <hip/hip_fp16.h>

#define FEAT 32
#define BIN_NODES 128
#define BIN_SHIFT 7
#define TILE_EDGES 8192
#define SRC_BITS 20
#define SRC_MASK 0xFFFFF

// Block-local int64-vs-int32 detection: odd 32-bit words of an int64 index
// array (values < 2^31) are all zero; for int32 they are random node ids
// (P(first 256 all zero) ~ (1e-5)^256). nz must point to shared memory.
__device__ __forceinline__ int block_detect_int64(const int* __restrict__ raw32, int* nz) {
    if (threadIdx.x == 0) *nz = 0;
    __syncthreads();
    if (raw32[2 * threadIdx.x + 1] != 0) *nz = 1;
    __syncthreads();
    return (*nz == 0) ? 1 : 0;
}

__device__ __forceinline__ int load_idx(const void* raw, int f, long long i) {
    return f ? (int)((const long long*)raw)[i] : ((const int*)raw)[i];
}

// Phase A: per-(tile,bin) histogram (mat[k*nb + b], tile-major) + zero deg.
__global__ void binA_kernel(const void* __restrict__ raw, int* __restrict__ mat,
                            int* __restrict__ deg, int e, int n, int nb) {
    extern __shared__ int hist[];  // nb + 1
    int t = threadIdx.x;
    for (int i = t; i < nb; i += 256) hist[i] = 0;
    int f = block_detect_int64((const int*)raw, &hist[nb]);  // syncs cover zeroing
    for (int i = blockIdx.x * 256 + t; i < n; i += gridDim.x * 256) deg[i] = 0;
    long long base = (long long)blockIdx.x * TILE_EDGES;
    int cnt = (int)min((long long)TILE_EDGES, (long long)e - base);
    for (int i = t; i < cnt; i += 256) {
        int d = load_idx(raw, f, (long long)e + base + i);
        atomicAdd(&hist[d >> BIN_SHIFT], 1);
    }
    __syncthreads();
    for (int b = t; b < nb; b += 256) mat[blockIdx.x * nb + b] = hist[b];
}

// logical L = b*nblk + k (bin-major) <-> physical p = k*nb + b
__device__ __forceinline__ int l2p(int L, int nb, int nblk) {
    int b = L / nblk;
    int k = L - b * nblk;
    return k * nb + b;
}

__global__ void scan1_kernel(int* __restrict__ mat, int* __restrict__ bsum,
                             int M, int nb, int nblk) {
    __shared__ int sd[256];
    int t = threadIdx.x;
    int L = blockIdx.x * 256 + t;
    int p = 0, v = 0;
    if (L < M) { p = l2p(L, nb, nblk); v = mat[p]; }
    sd[t] = v;
    __syncthreads();
    for (int off = 1; off < 256; off <<= 1) {
        int add = (t >= off) ? sd[t - off] : 0;
        __syncthreads();
        sd[t] += add;
        __syncthreads();
    }
    if (L < M) mat[p] = sd[t] - v;
    if (t == 255) bsum[blockIdx.x] = sd[t];
}

__global__ void scan2_kernel(int* __restrict__ bsum, int nbks) {
    __shared__ int sd[1024];
    int t = threadIdx.x;
    int v = (t < nbks) ? bsum[t] : 0;
    sd[t] = v;
    __syncthreads();
    for (int off = 1; off < 1024; off <<= 1) {
        int add = (t >= off) ? sd[t - off] : 0;
        __syncthreads();
        sd[t] += add;
        __syncthreads();
    }
    if (t < nbks) bsum[t] = sd[t] - v;
}

// Phase C: scatter packed records grouped by bin (bsum correction inlined) and
// count per-node in-degree. rec = src | dst_local<<20.
__global__ void binC_kernel(const void* __restrict__ raw, const int* __restrict__ mat,
                            const int* __restrict__ bsum, int* __restrict__ packed,
                            int* __restrict__ deg, int e, int nb, int nblk) {
    extern __shared__ int cur[];  // nb + 1
    int t = threadIdx.x;
    int f = block_detect_int64((const int*)raw, &cur[nb]);
    for (int i = t; i < nb; i += 256)
        cur[i] = mat[blockIdx.x * nb + i] + bsum[(i * nblk + blockIdx.x) >> 8];
    __syncthreads();
    long long base = (long long)blockIdx.x * TILE_EDGES;
    int cnt = (int)min((long long)TILE_EDGES, (long long)e - base);
    for (int i = t; i < cnt; i += 256) {
        long long ei = base + i;
        int s = load_idx(raw, f, ei);
        int d = load_idx(raw, f, (long long)e + ei);
        int b = d >> BIN_SHIFT;
        int pos = atomicAdd(&cur[b], 1);
        packed[pos] = s | ((d & (BIN_NODES - 1)) << SRC_BITS);
        atomicAdd(&deg[d], 1);
    }
}

// Single pass: per-bin LDS scan of deg -> dis/row_start, then counting-sort the
// bin's records into per-node CSR order. Records out = src only (4B).
__global__ void degsort_kernel(const int* __restrict__ packed, const int* __restrict__ mat,
                               const int* __restrict__ bsum, const int* __restrict__ deg,
                               float* __restrict__ dis, int* __restrict__ row_start,
                               int* __restrict__ recs, int e, int n, int nb, int nblk) {
    __shared__ int exc[BIN_NODES], cur[BIN_NODES];
    int b = blockIdx.x, t = threadIdx.x;
    int start = mat[b] + bsum[(b * nblk) >> 8];
    int end = (b + 1 < nb) ? (mat[b + 1] + bsum[((b + 1) * nblk) >> 8]) : e;
    int c = 0;
    if (t < BIN_NODES) {
        int node = b * BIN_NODES + t;
        c = (node < n) ? deg[node] : 0;
        exc[t] = c;
    }
    __syncthreads();
    for (int off = 1; off < BIN_NODES; off <<= 1) {
        int v = 0;
        if (t < BIN_NODES && t >= off) v = exc[t - off];
        __syncthreads();
        if (t < BIN_NODES) exc[t] += v;
        __syncthreads();
    }
    if (t < BIN_NODES) {
        int node = b * BIN_NODES + t;
        int rs = start + exc[t] - c;  // inclusive -> exclusive
        cur[t] = rs;
        if (node < n) {
            dis[node] = rsqrtf((float)c + 1.0f);
            row_start[node] = rs;
        }
    }
    __syncthreads();
    for (int i = start + t; i < end; i += 256) {
        int rec = packed[i];
        int pos = atomicAdd(&cur[rec >> SRC_BITS], 1);
        recs[pos] = rec & SRC_MASK;
    }
}

// h~ = fp16( dis * (act(in) @ W) )   (8 nodes x 32 lanes per block, W in LDS)
__global__ void matmul_kernel(const float* __restrict__ in, const float* __restrict__ W,
                              const float* __restrict__ dis, __half* __restrict__ h,
                              int n, int relu_in) {
    __shared__ float Wl[FEAT * FEAT];
    int tid = threadIdx.x;
    for (int i = tid; i < FEAT * FEAT; i += 256) Wl[i] = W[i];
    __syncthreads();
    int node = blockIdx.x * 8 + (tid >> 5);
    int j = tid & 31;
    if (node >= n) return;
    float xv = in[node * FEAT + j];
    if (relu_in) xv = fmaxf(xv, 0.0f);
    float sum = 0.0f;
#pragma unroll
    for (int k = 0; k < FEAT; ++k) sum = fmaf(__shfl(xv, k, 32), Wl[k * FEAT + j], sum);
    h[node * FEAT + j] = __float2half(dis[node] * sum);
}

// Pull: out[d] = act( dis[d] * (sum_{s in N(d)} h~[s] + h~[d]) + bias ).
// 32 lanes/node = 4 record-slots x 8 feature-lanes (4 halves = 8B each);
// one record's gather = 64B = 1 cache line; 8 predicated gathers in flight.
__global__ __launch_bounds__(256, 4)
void pull_kernel(const int* __restrict__ recs, const int* __restrict__ row_start,
                 const int* __restrict__ deg_arr, const __half* __restrict__ h,
                 const float* __restrict__ dis, const float* __restrict__ bias,
                 float* __restrict__ out, int n, int relu_out) {
    int t = threadIdx.x;
    int node = blockIdx.x * 8 + (t >> 5);
    if (node >= n) return;
    int l32 = t & 31;
    int sub = l32 >> 3;   // record slot 0..3
    int fb = l32 & 7;     // 4-half feature block
    int start = row_start[node];
    int deg = deg_arr[node];
    const float2* h2 = (const float2*)h;  // 4 halves per float2
    float4 sum = make_float4(0.0f, 0.0f, 0.0f, 0.0f);
    for (int r0 = 0; r0 < deg; r0 += 32) {
#pragma unroll
        for (int w = 0; w < 8; ++w) {
            int r = r0 + w * 4 + sub;
            if (r < deg) {
                int s = recs[start + r];
                float2 rv = h2[(size_t)s * 8 + fb];
                float2 f01 = __half22float2(*(const __half2*)&rv.x);
                float2 f23 = __half22float2(*(const __half2*)&rv.y);
                sum.x += f01.x; sum.y += f01.y; sum.z += f23.x; sum.w += f23.y;
            }
        }
    }
    sum.x += __shfl_xor(sum.x, 8, 64);  sum.y += __shfl_xor(sum.y, 8, 64);
    sum.z += __shfl_xor(sum.z, 8, 64);  sum.w += __shfl_xor(sum.w, 8, 64);
    sum.x += __shfl_xor(sum.x, 16, 64); sum.y += __shfl_xor(sum.y, 16, 64);
    sum.z += __shfl_xor(sum.z, 16, 64); sum.w += __shfl_xor(sum.w, 16, 64);
    if (sub == 0) {
        float dn = dis[node];
        float2 rv = h2[(size_t)node * 8 + fb];   // self-loop: + h~[node]
        float2 f01 = __half22float2(*(const __half2*)&rv.x);
        float2 f23 = __half22float2(*(const __half2*)&rv.y);
        float4 bv = ((const float4*)bias)[fb];
        float4 val;
        val.x = fmaf(dn, sum.x + f01.x, bv.x);
        val.y = fmaf(dn, sum.y + f01.y, bv.y);
        val.z = fmaf(dn, sum.z + f23.x, bv.z);
        val.w = fmaf(dn, sum.w + f23.y, bv.w);
        if (relu_out) {
            val.x = fmaxf(val.x, 0.0f); val.y = fmaxf(val.y, 0.0f);
            val.z = fmaxf(val.z, 0.0f); val.w = fmaxf(val.w, 0.0f);
        }
        ((float4*)out)[(size_t)node * 8 + fb] = val;
    }
}

extern "C" void kernel_launch(void* const* d_in, const int* in_sizes, int n_in,
                              void* d_out, int out_size, void* d_ws, size_t ws_size,
                              hipStream_t stream) {
    const float* x = (const float*)d_in[0];
    const void* eidx_raw = d_in[1];
    const float* W1 = (const float*)d_in[2];
    const float* b1 = (const float*)d_in[3];
    const float* W2 = (const float*)d_in[4];
    const float* b2 = (const float*)d_in[5];
    float* out = (float*)d_out;

    const int n = in_sizes[0] / FEAT;                    // 100000
    const int e = in_sizes[1] / 2;                       // 1600000
    const int nb = (n + BIN_NODES - 1) / BIN_NODES;      // 782
    const int nblk = (e + TILE_EDGES - 1) / TILE_EDGES;  // 196
    const int M = nb * nblk;
    const int nbks = (M + 255) / 256;                    // 599 <= 1024

    // Workspace (256B-aligned). `packed` aliases `acc1` (dead before pull1 writes).
    char* ws = (char*)d_ws;
    size_t off = 0;
    auto alloc = [&](size_t bytes) { char* p = ws + off; off = (off + bytes + 255) & ~(size_t)255; return p; };
    int*    mat       = (int*)   alloc((size_t)M * 4);
    int*    bsum      = (int*)   alloc((size_t)nbks * 4);
    float*  dis       = (float*) alloc((size_t)n * 4);
    int*    row_start = (int*)   alloc((size_t)n * 4);
    int*    deg       = (int*)   alloc((size_t)n * 4);
    int*    recs      = (int*)   alloc((size_t)e * 4);
    __half* h         = (__half*)alloc((size_t)n * FEAT * 2);
    float*  acc1      = (float*) alloc((size_t)n * FEAT * 4);
    int*    packed    = (int*)acc1;  // e*4 = 6.4MB <= 12.8MB, dead before pull1

    const size_t lds_bins = (size_t)(nb + 1) * 4;
    const int gNode = (n + 7) / 8;

    // CSR build (5 launches, single-pass sort)
    binA_kernel<<<nblk, 256, lds_bins, stream>>>(eidx_raw, mat, deg, e, n, nb);
    scan1_kernel<<<nbks, 256, 0, stream>>>(mat, bsum, M, nb, nblk);
    scan2_kernel<<<1, 1024, 0, stream>>>(bsum, nbks);
    binC_kernel<<<nblk, 256, lds_bins, stream>>>(eidx_raw, mat, bsum, packed, deg, e, nb, nblk);
    degsort_kernel<<<nb, 256, 0, stream>>>(packed, mat, bsum, deg, dis, row_start,
                                           recs, e, n, nb, nblk);

    // Layer 1
    matmul_kernel<<<gNode, 256, 0, stream>>>(x, W1, dis, h, n, 0);
    pull_kernel<<<gNode, 256, 0, stream>>>(recs, row_start, deg, h, dis, b1, acc1, n, 0);

    // Layer 2 (relu on read of acc1; final relu fused in writeout)
    matmul_kernel<<<gNode, 256, 0, stream>>>(acc1, W2, dis, h, n, 1);
    pull_kernel<<<gNode, 256, 0, stream>>>(recs, row_start, deg, h, dis, b2, out, n, 1);
}

// Round 7
// 250.941 us; speedup vs baseline: 1.2078x; 1.2078x over previous
//
#include <hip/hip_runtime.h>
#include <hip/hip_fp16.h>

#define FEAT 32
#define BIN_NODES 128
#define BIN_SHIFT 7
#define TILE_EDGES 8192
#define SRC_BITS 20
#define SRC_MASK 0xFFFFF

// Block-local int64-vs-int32 detection: odd 32-bit words of an int64 index
// array (values < 2^31) are all zero; for int32 they are random node ids.
__device__ __forceinline__ int block_detect_int64(const int* __restrict__ raw32, int* nz) {
    if (threadIdx.x == 0) *nz = 0;
    __syncthreads();
    if (raw32[2 * threadIdx.x + 1] != 0) *nz = 1;
    __syncthreads();
    return (*nz == 0) ? 1 : 0;
}

__device__ __forceinline__ int load_idx(const void* raw, int f, long long i) {
    return f ? (int)((const long long*)raw)[i] : ((const int*)raw)[i];
}

// Phase A: per-(tile,bin) histogram. mat layout: mat[k*nb + b] (tile-major).
__global__ void binA_kernel(const void* __restrict__ raw, int* __restrict__ mat,
                            int e, int nb) {
    extern __shared__ int hist[];  // nb + 1
    int t = threadIdx.x;
    for (int i = t; i < nb; i += 256) hist[i] = 0;
    int f = block_detect_int64((const int*)raw, &hist[nb]);  // syncs cover zeroing
    long long base = (long long)blockIdx.x * TILE_EDGES;
    int cnt = (int)min((long long)TILE_EDGES, (long long)e - base);
    for (int i = t; i < cnt; i += 256) {
        int d = load_idx(raw, f, (long long)e + base + i);
        atomicAdd(&hist[d >> BIN_SHIFT], 1);
    }
    __syncthreads();
    for (int b = t; b < nb; b += 256) mat[blockIdx.x * nb + b] = hist[b];
}

// logical L = b*nblk + k (bin-major) <-> physical p = k*nb + b
__device__ __forceinline__ int l2p(int L, int nb, int nblk) {
    int b = L / nblk;
    int k = L - b * nblk;
    return k * nb + b;
}

__global__ void scan1_kernel(int* __restrict__ mat, int* __restrict__ bsum,
                             int M, int nb, int nblk) {
    __shared__ int sd[256];
    int t = threadIdx.x;
    int L = blockIdx.x * 256 + t;
    int p = 0, v = 0;
    if (L < M) { p = l2p(L, nb, nblk); v = mat[p]; }
    sd[t] = v;
    __syncthreads();
    for (int off = 1; off < 256; off <<= 1) {
        int add = (t >= off) ? sd[t - off] : 0;
        __syncthreads();
        sd[t] += add;
        __syncthreads();
    }
    if (L < M) mat[p] = sd[t] - v;   // exclusive within scan-block
    if (t == 255) bsum[blockIdx.x] = sd[t];
}

__global__ void scan2_kernel(int* __restrict__ bsum, int nbks) {
    __shared__ int sd[1024];
    int t = threadIdx.x;
    int v = (t < nbks) ? bsum[t] : 0;
    sd[t] = v;
    __syncthreads();
    for (int off = 1; off < 1024; off <<= 1) {
        int add = (t >= off) ? sd[t - off] : 0;
        __syncthreads();
        sd[t] += add;
        __syncthreads();
    }
    if (t < nbks) bsum[t] = sd[t] - v;
}

// Phase C: scatter packed records grouped by bin (bsum correction inlined).
// rec = src | dst_local<<20. NO global atomics (round-6 lesson: per-edge global
// atomicAdd write-through cost 70MB of HBM writes).
__global__ void binC_kernel(const void* __restrict__ raw, const int* __restrict__ mat,
                            const int* __restrict__ bsum, int* __restrict__ packed,
                            int e, int nb, int nblk) {
    extern __shared__ int cur[];  // nb + 1
    int t = threadIdx.x;
    int f = block_detect_int64((const int*)raw, &cur[nb]);
    for (int i = t; i < nb; i += 256)
        cur[i] = mat[blockIdx.x * nb + i] + bsum[(i * nblk + blockIdx.x) >> 8];
    __syncthreads();
    long long base = (long long)blockIdx.x * TILE_EDGES;
    int cnt = (int)min((long long)TILE_EDGES, (long long)e - base);
    for (int i = t; i < cnt; i += 256) {
        long long ei = base + i;
        int s = load_idx(raw, f, ei);
        int d = load_idx(raw, f, (long long)e + ei);
        int b = d >> BIN_SHIFT;
        int pos = atomicAdd(&cur[b], 1);
        packed[pos] = s | ((d & (BIN_NODES - 1)) << SRC_BITS);
    }
}

// Two-pass per-bin: LDS histogram count -> scan -> dis/row_start, then
// counting-sort records into per-node CSR order. Records out = src only (4B).
// row_start has n+1 entries; row_start[n] = e sentinel (deg via difference).
__global__ void degsort_kernel(const int* __restrict__ packed, const int* __restrict__ mat,
                               const int* __restrict__ bsum, float* __restrict__ dis,
                               int* __restrict__ row_start, int* __restrict__ recs,
                               int e, int n, int nb, int nblk) {
    __shared__ int cnt[BIN_NODES], exc[BIN_NODES], cur[BIN_NODES];
    int b = blockIdx.x, t = threadIdx.x;
    if (t < BIN_NODES) cnt[t] = 0;
    __syncthreads();
    int start = mat[b] + bsum[(b * nblk) >> 8];
    int end = (b + 1 < nb) ? (mat[b + 1] + bsum[((b + 1) * nblk) >> 8]) : e;
    for (int i = start + t; i < end; i += 256) atomicAdd(&cnt[packed[i] >> SRC_BITS], 1);
    __syncthreads();
    if (t < BIN_NODES) exc[t] = cnt[t];
    __syncthreads();
    for (int off = 1; off < BIN_NODES; off <<= 1) {
        int v = 0;
        if (t < BIN_NODES && t >= off) v = exc[t - off];
        __syncthreads();
        if (t < BIN_NODES) exc[t] += v;
        __syncthreads();
    }
    if (t < BIN_NODES) {
        int node = b * BIN_NODES + t;
        int rs = start + exc[t] - cnt[t];   // inclusive -> exclusive
        cur[t] = rs;
        if (node < n) {
            dis[node] = rsqrtf((float)cnt[t] + 1.0f);
            row_start[node] = rs;
        }
    }
    if (b == nb - 1 && t == BIN_NODES) row_start[n] = e;  // sentinel
    __syncthreads();
    for (int i = start + t; i < end; i += 256) {
        int rec = packed[i];
        int pos = atomicAdd(&cur[rec >> SRC_BITS], 1);
        recs[pos] = rec & SRC_MASK;
    }
}

// h~ = fp16( dis * (act(in) @ W) )   (8 nodes x 32 lanes per block, W in LDS)
__global__ void matmul_kernel(const float* __restrict__ in, const float* __restrict__ W,
                              const float* __restrict__ dis, __half* __restrict__ h,
                              int n, int relu_in) {
    __shared__ float Wl[FEAT * FEAT];
    int tid = threadIdx.x;
    for (int i = tid; i < FEAT * FEAT; i += 256) Wl[i] = W[i];
    __syncthreads();
    int node = blockIdx.x * 8 + (tid >> 5);
    int j = tid & 31;
    if (node >= n) return;
    float xv = in[node * FEAT + j];
    if (relu_in) xv = fmaxf(xv, 0.0f);
    float sum = 0.0f;
#pragma unroll
    for (int k = 0; k < FEAT; ++k) sum = fmaf(__shfl(xv, k, 32), Wl[k * FEAT + j], sum);
    h[node * FEAT + j] = __float2half(dis[node] * sum);
}

// Pull: out[d] = act( dis[d] * (sum_{s in N(d)} h~[s] + h~[d]) + bias ).
// 32 lanes/node = 4 record-slots x 8 feature-lanes (4 halves = 8B each);
// one record's gather = 64B = 1 cache line; 8 predicated gathers in flight.
__global__ __launch_bounds__(256, 4)
void pull_kernel(const int* __restrict__ recs, const int* __restrict__ row_start,
                 const __half* __restrict__ h, const float* __restrict__ dis,
                 const float* __restrict__ bias, float* __restrict__ out,
                 int n, int relu_out) {
    int t = threadIdx.x;
    int node = blockIdx.x * 8 + (t >> 5);
    if (node >= n) return;
    int l32 = t & 31;
    int sub = l32 >> 3;   // record slot 0..3
    int fb = l32 & 7;     // 4-half feature block
    int start = row_start[node];
    int deg = row_start[node + 1] - start;
    const float2* h2 = (const float2*)h;  // 4 halves per float2
    float4 sum = make_float4(0.0f, 0.0f, 0.0f, 0.0f);
    for (int r0 = 0; r0 < deg; r0 += 32) {
#pragma unroll
        for (int w = 0; w < 8; ++w) {
            int r = r0 + w * 4 + sub;
            if (r < deg) {
                int s = recs[start + r];
                float2 rv = h2[(size_t)s * 8 + fb];
                float2 f01 = __half22float2(*(const __half2*)&rv.x);
                float2 f23 = __half22float2(*(const __half2*)&rv.y);
                sum.x += f01.x; sum.y += f01.y; sum.z += f23.x; sum.w += f23.y;
            }
        }
    }
    sum.x += __shfl_xor(sum.x, 8, 64);  sum.y += __shfl_xor(sum.y, 8, 64);
    sum.z += __shfl_xor(sum.z, 8, 64);  sum.w += __shfl_xor(sum.w, 8, 64);
    sum.x += __shfl_xor(sum.x, 16, 64); sum.y += __shfl_xor(sum.y, 16, 64);
    sum.z += __shfl_xor(sum.z, 16, 64); sum.w += __shfl_xor(sum.w, 16, 64);
    if (sub == 0) {
        float dn = dis[node];
        float2 rv = h2[(size_t)node * 8 + fb];   // self-loop: + h~[node]
        float2 f01 = __half22float2(*(const __half2*)&rv.x);
        float2 f23 = __half22float2(*(const __half2*)&rv.y);
        float4 bv = ((const float4*)bias)[fb];
        float4 val;
        val.x = fmaf(dn, sum.x + f01.x, bv.x);
        val.y = fmaf(dn, sum.y + f01.y, bv.y);
        val.z = fmaf(dn, sum.z + f23.x, bv.z);
        val.w = fmaf(dn, sum.w + f23.y, bv.w);
        if (relu_out) {
            val.x = fmaxf(val.x, 0.0f); val.y = fmaxf(val.y, 0.0f);
            val.z = fmaxf(val.z, 0.0f); val.w = fmaxf(val.w, 0.0f);
        }
        ((float4*)out)[(size_t)node * 8 + fb] = val;
    }
}

extern "C" void kernel_launch(void* const* d_in, const int* in_sizes, int n_in,
                              void* d_out, int out_size, void* d_ws, size_t ws_size,
                              hipStream_t stream) {
    const float* x = (const float*)d_in[0];
    const void* eidx_raw = d_in[1];
    const float* W1 = (const float*)d_in[2];
    const float* b1 = (const float*)d_in[3];
    const float* W2 = (const float*)d_in[4];
    const float* b2 = (const float*)d_in[5];
    float* out = (float*)d_out;

    const int n = in_sizes[0] / FEAT;                    // 100000
    const int e = in_sizes[1] / 2;                       // 1600000
    const int nb = (n + BIN_NODES - 1) / BIN_NODES;      // 782
    const int nblk = (e + TILE_EDGES - 1) / TILE_EDGES;  // 196
    const int M = nb * nblk;
    const int nbks = (M + 255) / 256;                    // 599 <= 1024

    // Workspace (256B-aligned). `packed` aliases `acc1` (dead before pull1 writes).
    char* ws = (char*)d_ws;
    size_t off = 0;
    auto alloc = [&](size_t bytes) { char* p = ws + off; off = (off + bytes + 255) & ~(size_t)255; return p; };
    int*    mat       = (int*)   alloc((size_t)M * 4);
    int*    bsum      = (int*)   alloc((size_t)nbks * 4);
    float*  dis       = (float*) alloc((size_t)n * 4);
    int*    row_start = (int*)   alloc((size_t)(n + 1) * 4);
    int*    recs      = (int*)   alloc((size_t)e * 4);
    __half* h         = (__half*)alloc((size_t)n * FEAT * 2);
    float*  acc1      = (float*) alloc((size_t)n * FEAT * 4);
    int*    packed    = (int*)acc1;  // e*4 = 6.4MB <= 12.8MB, dead before pull1

    const size_t lds_bins = (size_t)(nb + 1) * 4;
    const int gNode = (n + 7) / 8;

    // CSR build (5 launches, no global atomics)
    binA_kernel<<<nblk, 256, lds_bins, stream>>>(eidx_raw, mat, e, nb);
    scan1_kernel<<<nbks, 256, 0, stream>>>(mat, bsum, M, nb, nblk);
    scan2_kernel<<<1, 1024, 0, stream>>>(bsum, nbks);
    binC_kernel<<<nblk, 256, lds_bins, stream>>>(eidx_raw, mat, bsum, packed, e, nb, nblk);
    degsort_kernel<<<nb, 256, 0, stream>>>(packed, mat, bsum, dis, row_start,
                                           recs, e, n, nb, nblk);

    // Layer 1
    matmul_kernel<<<gNode, 256, 0, stream>>>(x, W1, dis, h, n, 0);
    pull_kernel<<<gNode, 256, 0, stream>>>(recs, row_start, h, dis, b1, acc1, n, 0);

    // Layer 2 (relu on read of acc1; final relu fused in writeout)
    matmul_kernel<<<gNode, 256, 0, stream>>>(acc1, W2, dis, h, n, 1);
    pull_kernel<<<gNode, 256, 0, stream>>>(recs, row_start, h, dis, b2, out, n, 1);
}